// Round 9
// baseline (197.909 us; speedup 1.0000x reference)
//
#include <hip/hip_runtime.h>
#include <hip/hip_bf16.h>

// Problem constants: B=4, L=2048, H=8, D=64, SAMPLE_K=N_TOP=40
#define BB 4
#define LL 2048
#define HH 8
#define DD 64
#define SK 40
#define NT 40
#define CH 256              // keys per attn chunk
#define NCH (LL / CH)       // 8 chunks per (b,h)
#define QH 20               // queries per attn block (40 split in 2)

// ---------------------------------------------------------------------------
// Kernel 1: M[bh][l] = max_s(q . k_{idx[l,s]}) - (sum_s q . k_{idx[l,s]}) / L
// Block = (b,l), XCD-swizzled (each XCD serves one b -> K[b] is L2-resident).
// BARRIER-FREE direct-L2 gather: thread (h,s0,q) = (t>>5, (t>>2)&7, t&3)
// loads its 16-float K fragment straight from L2; a quad covers 256 B
// contiguous so every 64-B granule is fully consumed. 5 phases (sample
// p*8+s0), 2-deep register prefetch; no LDS staging, no per-phase barriers
// -> 8 waves/SIMD hide the ~200-cyc L2 latency (round 8: LDS dbuf capped
// occupancy at 36% and spent 5 syncthreads; this removes both).
// Quad lanes hold duplicate dots after combine -> mean term /4.
// ---------------------------------------------------------------------------
__global__ __launch_bounds__(256) void compute_m_kernel(
        const float* __restrict__ Q, const float* __restrict__ K,
        const int* __restrict__ idx, float* __restrict__ M) {
    __shared__ int sidx[SK];

    int blk = blockIdx.x;
    int x = blk & 7, g = blk >> 3;
    int b = x >> 1;                    // XCD pair -> batch
    int l = (g << 1) | (x & 1);
    int t = threadIdx.x;

    if (t < SK) sidx[t] = idx[(size_t)l * SK + t];

    int q  = t & 3;                    // quarter (16 dims)
    int h  = t >> 5;                   // head 0..7
    int s0 = (t >> 2) & 7;             // sample-in-phase

    const float4* Qb = (const float4*)(Q + ((size_t)b * LL + l) * 512 + h * 64 + q * 16);
    float4 qf0 = Qb[0], qf1 = Qb[1], qf2 = Qb[2], qf3 = Qb[3];

    const float* Kb = K + (size_t)b * LL * 512 + h * 64 + q * 16;
    __syncthreads();                   // sidx ready (only barrier)

    // prefetch phase 0
    const float4* src = (const float4*)(Kb + (size_t)sidx[s0] * 512);
    float4 k0 = src[0], k1 = src[1], k2 = src[2], k3 = src[3];

    float mx = -INFINITY, sm = 0.0f;
    #pragma unroll
    for (int p = 0; p < 5; ++p) {
        float4 c0 = k0, c1 = k1, c2 = k2, c3 = k3;
        if (p < 4) {                   // prefetch next phase (stays in flight)
            const float4* s2 = (const float4*)(Kb + (size_t)sidx[(p + 1) * 8 + s0] * 512);
            k0 = s2[0]; k1 = s2[1]; k2 = s2[2]; k3 = s2[3];
        }
        float pd = qf0.x * c0.x + qf0.y * c0.y + qf0.z * c0.z + qf0.w * c0.w
                 + qf1.x * c1.x + qf1.y * c1.y + qf1.z * c1.z + qf1.w * c1.w
                 + qf2.x * c2.x + qf2.y * c2.y + qf2.z * c2.z + qf2.w * c2.w
                 + qf3.x * c3.x + qf3.y * c3.y + qf3.z * c3.z + qf3.w * c3.w;
        pd += __shfl_xor(pd, 1, 64);   // quad combine
        pd += __shfl_xor(pd, 2, 64);
        mx = fmaxf(mx, pd);
        sm += pd;
    }

    // reduce over the 32 lanes of each h-group (offsets <=16 stay in-half)
    #pragma unroll
    for (int off = 16; off >= 1; off >>= 1) {
        mx = fmaxf(mx, __shfl_xor(mx, off, 64));
        sm += __shfl_xor(sm, off, 64);
    }
    if ((t & 31) == 0)
        M[((size_t)b * HH + h) * LL + l] = mx - sm * (1.0f / (4.0f * (float)LL));
}

// ---------------------------------------------------------------------------
// Kernel 2: top-40 per (b,h), lower index wins ties. Incremental argmax.
// ---------------------------------------------------------------------------
__global__ __launch_bounds__(256) void topk_kernel(const float* __restrict__ M,
                                                   int* __restrict__ topi) {
    __shared__ unsigned long long keys[LL];   // 16 KB
    __shared__ unsigned long long wmax[4];
    __shared__ int win;
    int bh = blockIdx.x;
    int t  = threadIdx.x;
    int lane = t & 63, w = t >> 6;

    unsigned long long kmax = 0ULL;
    #pragma unroll
    for (int j = 0; j < 8; ++j) {
        int i = t + 256 * j;
        unsigned int bits = __float_as_uint(M[(size_t)bh * LL + i]);
        bits = (bits & 0x80000000u) ? ~bits : (bits | 0x80000000u);
        unsigned long long k = ((unsigned long long)bits << 11)
                             | (unsigned int)(LL - 1 - i);
        keys[i] = k;
        if (k > kmax) kmax = k;
    }
    __syncthreads();

    for (int u = 0; u < NT; ++u) {
        unsigned long long k = kmax;
        #pragma unroll
        for (int off = 32; off >= 1; off >>= 1) {
            unsigned long long o = __shfl_xor(k, off, 64);
            if (o > k) k = o;
        }
        if (lane == 0) wmax[w] = k;
        __syncthreads();
        if (t == 0) {
            unsigned long long k0 = wmax[0], k1 = wmax[1], k2 = wmax[2], k3 = wmax[3];
            if (k1 > k0) k0 = k1;
            if (k3 > k2) k0 = (k3 > k0) ? k3 : k0; else if (k2 > k0) k0 = k2;
            if (k2 > k0) k0 = k2;
            if (k3 > k0) k0 = k3;
            int i = (LL - 1) - (int)(k0 & 0x7FF);
            topi[bh * NT + u] = i;
            keys[i] = 0ULL;
            win = i;
        }
        __syncthreads();
        if ((win & 255) == t) {          // only the owner rescans
            kmax = 0ULL;
            #pragma unroll
            for (int j = 0; j < 8; ++j) {
                unsigned long long kk = keys[t + 256 * j];
                if (kk > kmax) kmax = kk;
            }
        }
    }
}

// ---------------------------------------------------------------------------
// Kernel 3: flash-chunked attention, query-split.
// __launch_bounds__(256,3) keeps kreg/vcol in registers (round 7 spill fix).
// (m,l) packed into one float2 store: halves write-allocate granule waste
// (round 8: two scalar stores cost ~1.3 MB of 64-B granules).
// ---------------------------------------------------------------------------
__global__ __launch_bounds__(256, 3) void attn_kernel(
        const float* __restrict__ Q, const float* __restrict__ K,
        const float* __restrict__ V, const int* __restrict__ topi,
        float2* __restrict__ pml, float* __restrict__ po) {
    __shared__ float  qs[QH][DD];        //  5120 B
    __shared__ float4 e4buf[4][64];      //  4096 B
    __shared__ float  oarea[4][QH][DD];  // 20480 B
    __shared__ float  mlarea[4][QH][2];  //   640 B

    int blk = blockIdx.x;
    int qh  = blk >> 8;                  // 0/1 query half
    int cc2 = blk & 255;
    int c   = cc2 & (NCH - 1);
    int bh  = cc2 >> 3;
    int h = bh & (HH - 1), b = bh >> 3;
    int t = threadIdx.x, lane = t & 63, w = t >> 6;
    int u0 = qh * QH;

    for (int i = t; i < QH * DD; i += 256) {
        int u = i >> 6, d = i & 63;
        int lq = topi[bh * NT + u0 + u];
        qs[u][d] = Q[(((size_t)b * LL + lq) * HH + h) * DD + d];
    }

    int key = c * CH + w * 64 + lane;
    const float4* kr = (const float4*)&K[(((size_t)b * LL + key) * HH + h) * DD];
    float4 kreg[16];
    #pragma unroll
    for (int j = 0; j < 16; ++j) kreg[j] = kr[j];

    float vcol[64];
    const float* vb = &V[(((size_t)b * LL + c * CH + w * 64) * HH + h) * DD + lane];
    #pragma unroll
    for (int j = 0; j < 64; ++j) vcol[j] = vb[(size_t)j * HH * DD];

    __syncthreads();   // qs ready

    for (int uq = 0; uq < QH / 4; ++uq) {
        float o0 = 0, o1 = 0, o2 = 0, o3 = 0;
        float mv0, mv1, mv2, mv3, lv0, lv1, lv2, lv3;
        float4 ev;
        #pragma unroll
        for (int j = 0; j < 4; ++j) {
            int u = uq * 4 + j;
            const float4* q4 = (const float4*)&qs[u][0];
            float s = 0.0f;
            #pragma unroll
            for (int cc = 0; cc < 16; ++cc) {
                float4 qv = q4[cc];
                s += qv.x * kreg[cc].x + qv.y * kreg[cc].y
                   + qv.z * kreg[cc].z + qv.w * kreg[cc].w;
            }
            s *= 0.125f;   // 1/sqrt(64)
            float m = s;
            #pragma unroll
            for (int off = 32; off >= 1; off >>= 1)
                m = fmaxf(m, __shfl_xor(m, off, 64));
            float e = __expf(s - m);
            float ls = e;
            #pragma unroll
            for (int off = 32; off >= 1; off >>= 1)
                ls += __shfl_xor(ls, off, 64);
            if (j == 0) { mv0 = m; lv0 = ls; ev.x = e; }
            if (j == 1) { mv1 = m; lv1 = ls; ev.y = e; }
            if (j == 2) { mv2 = m; lv2 = ls; ev.z = e; }
            if (j == 3) { mv3 = m; lv3 = ls; ev.w = e; }
        }
        e4buf[w][lane] = ev;
        asm volatile("s_waitcnt lgkmcnt(0)" ::: "memory");
        #pragma unroll
        for (int l2 = 0; l2 < 64; ++l2) {      // FULL unroll: vcol static
            float4 e = e4buf[w][l2];
            float  v = vcol[l2];
            o0 += e.x * v; o1 += e.y * v; o2 += e.z * v; o3 += e.w * v;
        }
        oarea[w][uq * 4 + 0][lane] = o0;
        oarea[w][uq * 4 + 1][lane] = o1;
        oarea[w][uq * 4 + 2][lane] = o2;
        oarea[w][uq * 4 + 3][lane] = o3;
        if (lane == 0) {
            mlarea[w][uq * 4 + 0][0] = mv0; mlarea[w][uq * 4 + 0][1] = lv0;
            mlarea[w][uq * 4 + 1][0] = mv1; mlarea[w][uq * 4 + 1][1] = lv1;
            mlarea[w][uq * 4 + 2][0] = mv2; mlarea[w][uq * 4 + 2][1] = lv2;
            mlarea[w][uq * 4 + 3][0] = mv3; mlarea[w][uq * 4 + 3][1] = lv3;
        }
    }
    __syncthreads();

    for (int i = t; i < QH * DD; i += 256) {
        int u = i >> 6, d = i & 63;
        float m0 = mlarea[0][u][0], m1 = mlarea[1][u][0];
        float m2 = mlarea[2][u][0], m3 = mlarea[3][u][0];
        float mb = fmaxf(fmaxf(m0, m1), fmaxf(m2, m3));
        float s0 = __expf(m0 - mb), s1 = __expf(m1 - mb);
        float s2 = __expf(m2 - mb), s3 = __expf(m3 - mb);
        float ob = oarea[0][u][d] * s0 + oarea[1][u][d] * s1
                 + oarea[2][u][d] * s2 + oarea[3][u][d] * s3;
        int gu = u0 + u;
        po[((size_t)(bh * NT + gu) * NCH + c) * DD + d] = ob;
        if (d == 0) {
            float lb = mlarea[0][u][1] * s0 + mlarea[1][u][1] * s1
                     + mlarea[2][u][1] * s2 + mlarea[3][u][1] * s3;
            pml[(bh * NT + gu) * NCH + c] = make_float2(mb, lb);
        }
    }
}

// ---------------------------------------------------------------------------
// Kernel 4: merge chunk partials. One wave per (bh,u), lane = d.
// ---------------------------------------------------------------------------
__global__ __launch_bounds__(256) void merge_kernel(
        const float2* __restrict__ pml, const float* __restrict__ po,
        float* __restrict__ out) {
    int wid  = blockIdx.x * 4 + (threadIdx.x >> 6);
    int lane = threadIdx.x & 63;
    int u  = wid % NT;
    int bh = wid / NT;
    int h = bh & (HH - 1), b = bh >> 3;
    int base = (bh * NT + u) * NCH;

    float m = -INFINITY;
    #pragma unroll
    for (int cc = 0; cc < NCH; ++cc) m = fmaxf(m, pml[base + cc].x);
    float lsum = 0.0f, o = 0.0f;
    #pragma unroll
    for (int cc = 0; cc < NCH; ++cc) {
        float2 ml = pml[base + cc];
        float sc = __expf(ml.x - m);
        lsum += ml.y * sc;
        o    += po[(size_t)(base + cc) * DD + lane] * sc;
    }
    out[(((size_t)b * NT + u) * HH + h) * DD + lane] = o / lsum;
}

extern "C" void kernel_launch(void* const* d_in, const int* in_sizes, int n_in,
                              void* d_out, int out_size, void* d_ws, size_t ws_size,
                              hipStream_t stream) {
    const float* Q   = (const float*)d_in[0];
    const float* K   = (const float*)d_in[1];
    const float* V   = (const float*)d_in[2];
    const int*   idx = (const int*)d_in[3];
    float* out = (float*)d_out;

    char* ws = (char*)d_ws;
    float*  M    = (float*)ws;                        ws += (size_t)BB * HH * LL * sizeof(float);
    int*    topi = (int*)ws;                          ws += (size_t)BB * HH * NT * sizeof(int);
    float2* pml  = (float2*)ws;                       ws += (size_t)BB * HH * NT * NCH * sizeof(float2);
    float*  po   = (float*)ws;                        // 2.62 MB

    hipLaunchKernelGGL(compute_m_kernel, dim3(BB * LL), dim3(256), 0, stream,
                       Q, K, idx, M);
    hipLaunchKernelGGL(topk_kernel, dim3(BB * HH), dim3(256), 0, stream, M, topi);
    hipLaunchKernelGGL(attn_kernel, dim3(2 * BB * HH * NCH), dim3(256), 0, stream,
                       Q, K, V, topi, pml, po);
    hipLaunchKernelGGL(merge_kernel, dim3(BB * HH * NT / 4), dim3(256), 0, stream,
                       pml, po, out);
}

// Round 10
// 177.424 us; speedup vs baseline: 1.1155x; 1.1155x over previous
//
#include <hip/hip_runtime.h>
#include <hip/hip_bf16.h>

// Problem constants: B=4, L=2048, H=8, D=64, SAMPLE_K=N_TOP=40
#define BB 4
#define LL 2048
#define HH 8
#define DD 64
#define SK 40
#define NT 40
#define CH 256              // keys per attn chunk
#define NCH (LL / CH)       // 8 chunks per (b,h)
#define QH 20               // queries per attn block (40 split in 2)

#define NPH 5               // compute_m phases
#define PH 8                // samples per phase
#define RS 516              // LDS row stride in dwords (2064 B = 129*16): 2-way banks (free), 16B-aligned
#define PBUF (PH * RS)      // 4128 dwords per buffer

typedef __attribute__((address_space(1))) const void* gl_ptr_t;
typedef __attribute__((address_space(3))) void*       lds_ptr_t;

// ---------------------------------------------------------------------------
// Kernel 1: M[bh][l] = max_s(q . k_{idx[l,s]}) - (sum_s q . k_{idx[l,s]}) / L
// Block = (b,l), XCD-swizzled (each XCD pair serves one b -> K[b] L2-resident).
// 5 phases x 8 samples. Staging via ASYNC global_load_lds width=16: per wave
// 4 instrs, each 64 lanes x 16 B contiguous (1 KB of one K row) -> optimal
// per-instruction coalescing (round 9 ERRATum: direct-gather scattered 16
// segments/instr and regressed 47->74 us). DMA for phase p+1 overlaps
// compute of phase p; __syncthreads drains vmcnt once per phase.
// Compute: quarter-dot per thread (t = h*32 + s0*4 + q), 2 DPP quad shuffles
// per sample, one 32-lane butterfly at the end; mean term /4 (quad dups).
// ---------------------------------------------------------------------------
__global__ __launch_bounds__(256) void compute_m_kernel(
        const float* __restrict__ Q, const float* __restrict__ K,
        const int* __restrict__ idx, float* __restrict__ M) {
    __shared__ float kbuf[2 * PBUF];   // 33 KB
    __shared__ int sidx[SK];

    int blk = blockIdx.x;
    int x = blk & 7, g = blk >> 3;
    int b = x >> 1;                    // XCD pair -> batch
    int l = (g << 1) | (x & 1);
    int t = threadIdx.x;

    if (t < SK) sidx[t] = idx[(size_t)l * SK + t];

    // quarter-dot mapping
    int q  = t & 3;                    // quarter (16 dims)
    int h  = t >> 5;                   // head 0..7
    int s0 = (t >> 2) & 7;             // sample-in-phase

    const float4* Qb = (const float4*)(Q + ((size_t)b * LL + l) * 512 + h * 64 + q * 16);
    float4 qf0 = Qb[0], qf1 = Qb[1], qf2 = Qb[2], qf3 = Qb[3];

    const float* Kb = K + (size_t)b * LL * 512;

    int wv   = t >> 6;                 // wave 0..3 (stages rows 2wv, 2wv+1)
    int lane = t & 63;
    __syncthreads();                   // sidx ready

    // async stage: phase p -> buffer buf (wave-uniform LDS base + lane*16)
    #define STAGE(p, buf) do {                                                  \
        _Pragma("unroll")                                                       \
        for (int i = 0; i < 4; ++i) {                                           \
            int r  = wv * 2 + (i >> 1);                                         \
            int hf = i & 1;                                                     \
            const float* gsrc = Kb + (size_t)sidx[(p) * PH + r] * 512           \
                              + hf * 256 + lane * 4;                            \
            float* ldst = kbuf + (buf) * PBUF + r * RS + hf * 256;              \
            __builtin_amdgcn_global_load_lds((gl_ptr_t)gsrc, (lds_ptr_t)ldst,   \
                                             16, 0, 0);                         \
        }                                                                       \
    } while (0)

    STAGE(0, 0);
    __syncthreads();                   // drains vmcnt: buffer 0 ready

    float mx = -INFINITY, sm = 0.0f;
    #pragma unroll
    for (int p = 0; p < NPH; ++p) {
        if (p < NPH - 1) STAGE(p + 1, (p + 1) & 1);   // async, overlaps compute
        const float* kb = kbuf + (p & 1) * PBUF + s0 * RS + h * 64 + q * 16;
        float4 k0 = *(const float4*)(kb);
        float4 k1 = *(const float4*)(kb + 4);
        float4 k2 = *(const float4*)(kb + 8);
        float4 k3 = *(const float4*)(kb + 12);
        float pd = qf0.x * k0.x + qf0.y * k0.y + qf0.z * k0.z + qf0.w * k0.w
                 + qf1.x * k1.x + qf1.y * k1.y + qf1.z * k1.z + qf1.w * k1.w
                 + qf2.x * k2.x + qf2.y * k2.y + qf2.z * k2.z + qf2.w * k2.w
                 + qf3.x * k3.x + qf3.y * k3.y + qf3.z * k3.z + qf3.w * k3.w;
        pd += __shfl_xor(pd, 1, 64);   // quad combine (DPP)
        pd += __shfl_xor(pd, 2, 64);
        mx = fmaxf(mx, pd);
        sm += pd;
        if (p < NPH - 1) __syncthreads();   // drains vmcnt: next buffer ready
    }
    #undef STAGE

    // reduce over the 32 lanes of each h-group (offsets <=16 stay in-half)
    #pragma unroll
    for (int off = 16; off >= 1; off >>= 1) {
        mx = fmaxf(mx, __shfl_xor(mx, off, 64));
        sm += __shfl_xor(sm, off, 64);
    }
    if ((t & 31) == 0)
        M[((size_t)b * HH + h) * LL + l] = mx - sm * (1.0f / (4.0f * (float)LL));
}

// ---------------------------------------------------------------------------
// Kernel 2: top-40 per (b,h), lower index wins ties. Incremental argmax.
// ---------------------------------------------------------------------------
__global__ __launch_bounds__(256) void topk_kernel(const float* __restrict__ M,
                                                   int* __restrict__ topi) {
    __shared__ unsigned long long keys[LL];   // 16 KB
    __shared__ unsigned long long wmax[4];
    __shared__ int win;
    int bh = blockIdx.x;
    int t  = threadIdx.x;
    int lane = t & 63, w = t >> 6;

    unsigned long long kmax = 0ULL;
    #pragma unroll
    for (int j = 0; j < 8; ++j) {
        int i = t + 256 * j;
        unsigned int bits = __float_as_uint(M[(size_t)bh * LL + i]);
        bits = (bits & 0x80000000u) ? ~bits : (bits | 0x80000000u);
        unsigned long long k = ((unsigned long long)bits << 11)
                             | (unsigned int)(LL - 1 - i);
        keys[i] = k;
        if (k > kmax) kmax = k;
    }
    __syncthreads();

    for (int u = 0; u < NT; ++u) {
        unsigned long long k = kmax;
        #pragma unroll
        for (int off = 32; off >= 1; off >>= 1) {
            unsigned long long o = __shfl_xor(k, off, 64);
            if (o > k) k = o;
        }
        if (lane == 0) wmax[w] = k;
        __syncthreads();
        if (t == 0) {
            unsigned long long k0 = wmax[0];
            if (wmax[1] > k0) k0 = wmax[1];
            if (wmax[2] > k0) k0 = wmax[2];
            if (wmax[3] > k0) k0 = wmax[3];
            int i = (LL - 1) - (int)(k0 & 0x7FF);
            topi[bh * NT + u] = i;
            keys[i] = 0ULL;
            win = i;
        }
        __syncthreads();
        if ((win & 255) == t) {          // only the owner rescans
            kmax = 0ULL;
            #pragma unroll
            for (int j = 0; j < 8; ++j) {
                unsigned long long kk = keys[t + 256 * j];
                if (kk > kmax) kmax = kk;
            }
        }
    }
}

// ---------------------------------------------------------------------------
// Kernel 3: flash-chunked attention, query-split.
// __launch_bounds__(256,3) keeps kreg/vcol in registers (round 7 spill fix).
// (m,l) packed float2 store (round 8 granule-waste fix).
// ---------------------------------------------------------------------------
__global__ __launch_bounds__(256, 3) void attn_kernel(
        const float* __restrict__ Q, const float* __restrict__ K,
        const float* __restrict__ V, const int* __restrict__ topi,
        float2* __restrict__ pml, float* __restrict__ po) {
    __shared__ float  qs[QH][DD];        //  5120 B
    __shared__ float4 e4buf[4][64];      //  4096 B
    __shared__ float  oarea[4][QH][DD];  // 20480 B
    __shared__ float  mlarea[4][QH][2];  //   640 B

    int blk = blockIdx.x;
    int qh  = blk >> 8;                  // 0/1 query half
    int cc2 = blk & 255;
    int c   = cc2 & (NCH - 1);
    int bh  = cc2 >> 3;
    int h = bh & (HH - 1), b = bh >> 3;
    int t = threadIdx.x, lane = t & 63, w = t >> 6;
    int u0 = qh * QH;

    for (int i = t; i < QH * DD; i += 256) {
        int u = i >> 6, d = i & 63;
        int lq = topi[bh * NT + u0 + u];
        qs[u][d] = Q[(((size_t)b * LL + lq) * HH + h) * DD + d];
    }

    int key = c * CH + w * 64 + lane;
    const float4* kr = (const float4*)&K[(((size_t)b * LL + key) * HH + h) * DD];
    float4 kreg[16];
    #pragma unroll
    for (int j = 0; j < 16; ++j) kreg[j] = kr[j];

    float vcol[64];
    const float* vb = &V[(((size_t)b * LL + c * CH + w * 64) * HH + h) * DD + lane];
    #pragma unroll
    for (int j = 0; j < 64; ++j) vcol[j] = vb[(size_t)j * HH * DD];

    __syncthreads();   // qs ready

    for (int uq = 0; uq < QH / 4; ++uq) {
        float o0 = 0, o1 = 0, o2 = 0, o3 = 0;
        float mv0, mv1, mv2, mv3, lv0, lv1, lv2, lv3;
        float4 ev;
        #pragma unroll
        for (int j = 0; j < 4; ++j) {
            int u = uq * 4 + j;
            const float4* q4 = (const float4*)&qs[u][0];
            float s = 0.0f;
            #pragma unroll
            for (int cc = 0; cc < 16; ++cc) {
                float4 qv = q4[cc];
                s += qv.x * kreg[cc].x + qv.y * kreg[cc].y
                   + qv.z * kreg[cc].z + qv.w * kreg[cc].w;
            }
            s *= 0.125f;   // 1/sqrt(64)
            float m = s;
            #pragma unroll
            for (int off = 32; off >= 1; off >>= 1)
                m = fmaxf(m, __shfl_xor(m, off, 64));
            float e = __expf(s - m);
            float ls = e;
            #pragma unroll
            for (int off = 32; off >= 1; off >>= 1)
                ls += __shfl_xor(ls, off, 64);
            if (j == 0) { mv0 = m; lv0 = ls; ev.x = e; }
            if (j == 1) { mv1 = m; lv1 = ls; ev.y = e; }
            if (j == 2) { mv2 = m; lv2 = ls; ev.z = e; }
            if (j == 3) { mv3 = m; lv3 = ls; ev.w = e; }
        }
        e4buf[w][lane] = ev;
        asm volatile("s_waitcnt lgkmcnt(0)" ::: "memory");
        #pragma unroll
        for (int l2 = 0; l2 < 64; ++l2) {      // FULL unroll: vcol static
            float4 e = e4buf[w][l2];
            float  v = vcol[l2];
            o0 += e.x * v; o1 += e.y * v; o2 += e.z * v; o3 += e.w * v;
        }
        oarea[w][uq * 4 + 0][lane] = o0;
        oarea[w][uq * 4 + 1][lane] = o1;
        oarea[w][uq * 4 + 2][lane] = o2;
        oarea[w][uq * 4 + 3][lane] = o3;
        if (lane == 0) {
            mlarea[w][uq * 4 + 0][0] = mv0; mlarea[w][uq * 4 + 0][1] = lv0;
            mlarea[w][uq * 4 + 1][0] = mv1; mlarea[w][uq * 4 + 1][1] = lv1;
            mlarea[w][uq * 4 + 2][0] = mv2; mlarea[w][uq * 4 + 2][1] = lv2;
            mlarea[w][uq * 4 + 3][0] = mv3; mlarea[w][uq * 4 + 3][1] = lv3;
        }
    }
    __syncthreads();

    for (int i = t; i < QH * DD; i += 256) {
        int u = i >> 6, d = i & 63;
        float m0 = mlarea[0][u][0], m1 = mlarea[1][u][0];
        float m2 = mlarea[2][u][0], m3 = mlarea[3][u][0];
        float mb = fmaxf(fmaxf(m0, m1), fmaxf(m2, m3));
        float s0 = __expf(m0 - mb), s1 = __expf(m1 - mb);
        float s2 = __expf(m2 - mb), s3 = __expf(m3 - mb);
        float ob = oarea[0][u][d] * s0 + oarea[1][u][d] * s1
                 + oarea[2][u][d] * s2 + oarea[3][u][d] * s3;
        int gu = u0 + u;
        po[((size_t)(bh * NT + gu) * NCH + c) * DD + d] = ob;
        if (d == 0) {
            float lb = mlarea[0][u][1] * s0 + mlarea[1][u][1] * s1
                     + mlarea[2][u][1] * s2 + mlarea[3][u][1] * s3;
            pml[(bh * NT + gu) * NCH + c] = make_float2(mb, lb);
        }
    }
}

// ---------------------------------------------------------------------------
// Kernel 4: merge chunk partials. One wave per (bh,u), lane = d.
// ---------------------------------------------------------------------------
__global__ __launch_bounds__(256) void merge_kernel(
        const float2* __restrict__ pml, const float* __restrict__ po,
        float* __restrict__ out) {
    int wid  = blockIdx.x * 4 + (threadIdx.x >> 6);
    int lane = threadIdx.x & 63;
    int u  = wid % NT;
    int bh = wid / NT;
    int h = bh & (HH - 1), b = bh >> 3;
    int base = (bh * NT + u) * NCH;

    float m = -INFINITY;
    #pragma unroll
    for (int cc = 0; cc < NCH; ++cc) m = fmaxf(m, pml[base + cc].x);
    float lsum = 0.0f, o = 0.0f;
    #pragma unroll
    for (int cc = 0; cc < NCH; ++cc) {
        float2 ml = pml[base + cc];
        float sc = __expf(ml.x - m);
        lsum += ml.y * sc;
        o    += po[(size_t)(base + cc) * DD + lane] * sc;
    }
    out[(((size_t)b * NT + u) * HH + h) * DD + lane] = o / lsum;
}

extern "C" void kernel_launch(void* const* d_in, const int* in_sizes, int n_in,
                              void* d_out, int out_size, void* d_ws, size_t ws_size,
                              hipStream_t stream) {
    const float* Q   = (const float*)d_in[0];
    const float* K   = (const float*)d_in[1];
    const float* V   = (const float*)d_in[2];
    const int*   idx = (const int*)d_in[3];
    float* out = (float*)d_out;

    char* ws = (char*)d_ws;
    float*  M    = (float*)ws;                        ws += (size_t)BB * HH * LL * sizeof(float);
    int*    topi = (int*)ws;                          ws += (size_t)BB * HH * NT * sizeof(int);
    float2* pml  = (float2*)ws;                       ws += (size_t)BB * HH * NT * NCH * sizeof(float2);
    float*  po   = (float*)ws;                        // 2.62 MB

    hipLaunchKernelGGL(compute_m_kernel, dim3(BB * LL), dim3(256), 0, stream,
                       Q, K, idx, M);
    hipLaunchKernelGGL(topk_kernel, dim3(BB * HH), dim3(256), 0, stream, M, topi);
    hipLaunchKernelGGL(attn_kernel, dim3(2 * BB * HH * NCH), dim3(256), 0, stream,
                       Q, K, V, topi, pml, po);
    hipLaunchKernelGGL(merge_kernel, dim3(BB * HH * NT / 4), dim3(256), 0, stream,
                       pml, po, out);
}

// Round 12
// 174.130 us; speedup vs baseline: 1.1366x; 1.0189x over previous
//
#include <hip/hip_runtime.h>
#include <hip/hip_bf16.h>

// Problem constants: B=4, L=2048, H=8, D=64, SAMPLE_K=N_TOP=40
#define BB 4
#define LL 2048
#define HH 8
#define DD 64
#define SK 40
#define NT 40
#define CH 256              // keys per attn chunk
#define NCH (LL / CH)       // 8 chunks per (b,h)
#define QH 20               // queries per attn block (40 split in 2)

#define WS 10               // samples per wave (4 waves x 10 = 40)
#define RS 516              // LDS row stride in dwords (2064 B): round-8 measured conflict-free shapes

// ---------------------------------------------------------------------------
// Kernel 1: M[bh][l] = max_s(q . k_{idx[l,s]}) - (sum_s q . k_{idx[l,s]}) / L
// Block = (b,l), XCD-swizzled (each XCD pair serves one b -> K[b] L2-resident).
// WAVE-PRIVATE pipeline, VGPR staging (round 11 ERRATUM: global_load_lds DMA
// with no vmcnt wait raced the consuming ds_read -> stale LDS -> rank skew;
// VGPR->ds_write makes every dependence compiler-visible, and the one
// LDS-write->read hazard is per-wave: explicit s_waitcnt lgkmcnt(0), the
// pattern already proven in attn_kernel). No block barriers in the pipeline:
// waves free-run against L2. Each wave owns 10 samples in 5 pairs, double-
// buffered in its own LDS slots. Staging lane r=lane>>5, cw=lane&31 loads
// 4 float4 at +0/+128/+256/+384 dwords (2x512B segments per instruction);
// compute lane s_lo*32+h*4+q reads 16 contiguous floats. 2 quad shuffles per
// sample + xor-32 merge + tiny 4-wave LDS combine (2 barriers total).
// ---------------------------------------------------------------------------
__global__ __launch_bounds__(256) void compute_m_kernel(
        const float* __restrict__ Q, const float* __restrict__ K,
        const int* __restrict__ idx, float* __restrict__ M) {
    __shared__ float kbuf[4][2][2 * RS];   // 4 waves x 2 slots x 2 rows = 33 KB
    __shared__ int sidx[SK];
    __shared__ float2 mlpart[4][HH];

    int blk = blockIdx.x;
    int x = blk & 7, g = blk >> 3;
    int b = x >> 1;                    // XCD pair -> batch
    int l = (g << 1) | (x & 1);
    int t = threadIdx.x;

    if (t < SK) sidx[t] = idx[(size_t)l * SK + t];

    int lane = t & 63, w = t >> 6;
    int s_lo = lane >> 5;              // which sample of the pair
    int h    = (lane >> 2) & 7;        // head
    int q    = lane & 3;               // 16-dim quarter

    const float4* Qb = (const float4*)(Q + ((size_t)b * LL + l) * 512 + h * 64 + q * 16);
    float4 qf0 = Qb[0], qf1 = Qb[1], qf2 = Qb[2], qf3 = Qb[3];

    const float* Kb = K + (size_t)b * LL * 512;

    int r  = lane >> 5;                // staging row of the pair
    int cw = lane & 31;
    __syncthreads();                   // sidx ready

    float4 g0, g1, g2, g3;
    #define LOADP(p) do {                                                       \
        const float* src = Kb + (size_t)sidx[w * WS + (p) * 2 + r] * 512        \
                         + cw * 4;                                              \
        g0 = *(const float4*)(src);                                             \
        g1 = *(const float4*)(src + 128);                                       \
        g2 = *(const float4*)(src + 256);                                       \
        g3 = *(const float4*)(src + 384);                                       \
    } while (0)
    #define WRITEP(slot) do {                                                   \
        float* dst = &kbuf[w][slot][r * RS + cw * 4];                           \
        *(float4*)(dst)       = g0;                                             \
        *(float4*)(dst + 128) = g1;                                             \
        *(float4*)(dst + 256) = g2;                                             \
        *(float4*)(dst + 384) = g3;                                             \
    } while (0)

    LOADP(0);
    WRITEP(0);

    float mx = -INFINITY, sm = 0.0f;
    #pragma unroll
    for (int p = 0; p < WS / 2; ++p) {
        if (p < WS / 2 - 1) LOADP(p + 1);          // global loads in flight
        asm volatile("s_waitcnt lgkmcnt(0)" ::: "memory");  // slot p&1 landed (per-wave)
        const float* kb = &kbuf[w][p & 1][s_lo * RS + h * 64 + q * 16];
        float4 k0 = *(const float4*)(kb);
        float4 k1 = *(const float4*)(kb + 4);
        float4 k2 = *(const float4*)(kb + 8);
        float4 k3 = *(const float4*)(kb + 12);
        float pd = qf0.x * k0.x + qf0.y * k0.y + qf0.z * k0.z + qf0.w * k0.w
                 + qf1.x * k1.x + qf1.y * k1.y + qf1.z * k1.z + qf1.w * k1.w
                 + qf2.x * k2.x + qf2.y * k2.y + qf2.z * k2.z + qf2.w * k2.w
                 + qf3.x * k3.x + qf3.y * k3.y + qf3.z * k3.z + qf3.w * k3.w;
        pd += __shfl_xor(pd, 1, 64);   // quad combine -> full dot
        pd += __shfl_xor(pd, 2, 64);
        mx = fmaxf(mx, pd);
        sm += pd;
        if (p < WS / 2 - 1) WRITEP((p + 1) & 1);   // compiler waits vmcnt for g*
    }
    #undef LOADP
    #undef WRITEP

    // merge the two pair-halves (lane ^ 32 holds the other sample's stats)
    mx = fmaxf(mx, __shfl_xor(mx, 32, 64));
    sm += __shfl_xor(sm, 32, 64);

    if ((lane & 0x23) == 0)            // q==0 && s_lo==0 -> lane = h*4
        mlpart[w][h] = make_float2(mx, sm);
    __syncthreads();

    if (t < HH) {
        float MX = -INFINITY, SM = 0.0f;
        #pragma unroll
        for (int w2 = 0; w2 < 4; ++w2) {
            float2 ml = mlpart[w2][t];
            MX = fmaxf(MX, ml.x);
            SM += ml.y;
        }
        M[((size_t)b * HH + t) * LL + l] = MX - SM * (1.0f / (float)LL);
    }
}

// ---------------------------------------------------------------------------
// Kernel 2: top-40 per (b,h), lower index wins ties. Incremental argmax.
// ---------------------------------------------------------------------------
__global__ __launch_bounds__(256) void topk_kernel(const float* __restrict__ M,
                                                   int* __restrict__ topi) {
    __shared__ unsigned long long keys[LL];   // 16 KB
    __shared__ unsigned long long wmax[4];
    __shared__ int win;
    int bh = blockIdx.x;
    int t  = threadIdx.x;
    int lane = t & 63, w = t >> 6;

    unsigned long long kmax = 0ULL;
    #pragma unroll
    for (int j = 0; j < 8; ++j) {
        int i = t + 256 * j;
        unsigned int bits = __float_as_uint(M[(size_t)bh * LL + i]);
        bits = (bits & 0x80000000u) ? ~bits : (bits | 0x80000000u);
        unsigned long long k = ((unsigned long long)bits << 11)
                             | (unsigned int)(LL - 1 - i);
        keys[i] = k;
        if (k > kmax) kmax = k;
    }
    __syncthreads();

    for (int u = 0; u < NT; ++u) {
        unsigned long long k = kmax;
        #pragma unroll
        for (int off = 32; off >= 1; off >>= 1) {
            unsigned long long o = __shfl_xor(k, off, 64);
            if (o > k) k = o;
        }
        if (lane == 0) wmax[w] = k;
        __syncthreads();
        if (t == 0) {
            unsigned long long k0 = wmax[0];
            if (wmax[1] > k0) k0 = wmax[1];
            if (wmax[2] > k0) k0 = wmax[2];
            if (wmax[3] > k0) k0 = wmax[3];
            int i = (LL - 1) - (int)(k0 & 0x7FF);
            topi[bh * NT + u] = i;
            keys[i] = 0ULL;
            win = i;
        }
        __syncthreads();
        if ((win & 255) == t) {          // only the owner rescans
            kmax = 0ULL;
            #pragma unroll
            for (int j = 0; j < 8; ++j) {
                unsigned long long kk = keys[t + 256 * j];
                if (kk > kmax) kmax = kk;
            }
        }
    }
}

// ---------------------------------------------------------------------------
// Kernel 3: flash-chunked attention, query-split.
// __launch_bounds__(256,3) keeps kreg/vcol in registers (round 7 spill fix).
// (m,l) packed float2 store (round 8 granule-waste fix).
// ---------------------------------------------------------------------------
__global__ __launch_bounds__(256, 3) void attn_kernel(
        const float* __restrict__ Q, const float* __restrict__ K,
        const float* __restrict__ V, const int* __restrict__ topi,
        float2* __restrict__ pml, float* __restrict__ po) {
    __shared__ float  qs[QH][DD];        //  5120 B
    __shared__ float4 e4buf[4][64];      //  4096 B
    __shared__ float  oarea[4][QH][DD];  // 20480 B
    __shared__ float  mlarea[4][QH][2];  //   640 B

    int blk = blockIdx.x;
    int qh  = blk >> 8;                  // 0/1 query half
    int cc2 = blk & 255;
    int c   = cc2 & (NCH - 1);
    int bh  = cc2 >> 3;
    int h = bh & (HH - 1), b = bh >> 3;
    int t = threadIdx.x, lane = t & 63, w = t >> 6;
    int u0 = qh * QH;

    for (int i = t; i < QH * DD; i += 256) {
        int u = i >> 6, d = i & 63;
        int lq = topi[bh * NT + u0 + u];
        qs[u][d] = Q[(((size_t)b * LL + lq) * HH + h) * DD + d];
    }

    int key = c * CH + w * 64 + lane;
    const float4* kr = (const float4*)&K[(((size_t)b * LL + key) * HH + h) * DD];
    float4 kreg[16];
    #pragma unroll
    for (int j = 0; j < 16; ++j) kreg[j] = kr[j];

    float vcol[64];
    const float* vb = &V[(((size_t)b * LL + c * CH + w * 64) * HH + h) * DD + lane];
    #pragma unroll
    for (int j = 0; j < 64; ++j) vcol[j] = vb[(size_t)j * HH * DD];

    __syncthreads();   // qs ready

    for (int uq = 0; uq < QH / 4; ++uq) {
        float o0 = 0, o1 = 0, o2 = 0, o3 = 0;
        float mv0, mv1, mv2, mv3, lv0, lv1, lv2, lv3;
        float4 ev;
        #pragma unroll
        for (int j = 0; j < 4; ++j) {
            int u = uq * 4 + j;
            const float4* q4 = (const float4*)&qs[u][0];
            float s = 0.0f;
            #pragma unroll
            for (int cc = 0; cc < 16; ++cc) {
                float4 qv = q4[cc];
                s += qv.x * kreg[cc].x + qv.y * kreg[cc].y
                   + qv.z * kreg[cc].z + qv.w * kreg[cc].w;
            }
            s *= 0.125f;   // 1/sqrt(64)
            float m = s;
            #pragma unroll
            for (int off = 32; off >= 1; off >>= 1)
                m = fmaxf(m, __shfl_xor(m, off, 64));
            float e = __expf(s - m);
            float ls = e;
            #pragma unroll
            for (int off = 32; off >= 1; off >>= 1)
                ls += __shfl_xor(ls, off, 64);
            if (j == 0) { mv0 = m; lv0 = ls; ev.x = e; }
            if (j == 1) { mv1 = m; lv1 = ls; ev.y = e; }
            if (j == 2) { mv2 = m; lv2 = ls; ev.z = e; }
            if (j == 3) { mv3 = m; lv3 = ls; ev.w = e; }
        }
        e4buf[w][lane] = ev;
        asm volatile("s_waitcnt lgkmcnt(0)" ::: "memory");
        #pragma unroll
        for (int l2 = 0; l2 < 64; ++l2) {      // FULL unroll: vcol static
            float4 e = e4buf[w][l2];
            float  v = vcol[l2];
            o0 += e.x * v; o1 += e.y * v; o2 += e.z * v; o3 += e.w * v;
        }
        oarea[w][uq * 4 + 0][lane] = o0;
        oarea[w][uq * 4 + 1][lane] = o1;
        oarea[w][uq * 4 + 2][lane] = o2;
        oarea[w][uq * 4 + 3][lane] = o3;
        if (lane == 0) {
            mlarea[w][uq * 4 + 0][0] = mv0; mlarea[w][uq * 4 + 0][1] = lv0;
            mlarea[w][uq * 4 + 1][0] = mv1; mlarea[w][uq * 4 + 1][1] = lv1;
            mlarea[w][uq * 4 + 2][0] = mv2; mlarea[w][uq * 4 + 2][1] = lv2;
            mlarea[w][uq * 4 + 3][0] = mv3; mlarea[w][uq * 4 + 3][1] = lv3;
        }
    }
    __syncthreads();

    for (int i = t; i < QH * DD; i += 256) {
        int u = i >> 6, d = i & 63;
        float m0 = mlarea[0][u][0], m1 = mlarea[1][u][0];
        float m2 = mlarea[2][u][0], m3 = mlarea[3][u][0];
        float mb = fmaxf(fmaxf(m0, m1), fmaxf(m2, m3));
        float s0 = __expf(m0 - mb), s1 = __expf(m1 - mb);
        float s2 = __expf(m2 - mb), s3 = __expf(m3 - mb);
        float ob = oarea[0][u][d] * s0 + oarea[1][u][d] * s1
                 + oarea[2][u][d] * s2 + oarea[3][u][d] * s3;
        int gu = u0 + u;
        po[((size_t)(bh * NT + gu) * NCH + c) * DD + d] = ob;
        if (d == 0) {
            float lb = mlarea[0][u][1] * s0 + mlarea[1][u][1] * s1
                     + mlarea[2][u][1] * s2 + mlarea[3][u][1] * s3;
            pml[(bh * NT + gu) * NCH + c] = make_float2(mb, lb);
        }
    }
}

// ---------------------------------------------------------------------------
// Kernel 4: merge chunk partials. One wave per (bh,u), lane = d.
// ---------------------------------------------------------------------------
__global__ __launch_bounds__(256) void merge_kernel(
        const float2* __restrict__ pml, const float* __restrict__ po,
        float* __restrict__ out) {
    int wid  = blockIdx.x * 4 + (threadIdx.x >> 6);
    int lane = threadIdx.x & 63;
    int u  = wid % NT;
    int bh = wid / NT;
    int h = bh & (HH - 1), b = bh >> 3;
    int base = (bh * NT + u) * NCH;

    float m = -INFINITY;
    #pragma unroll
    for (int cc = 0; cc < NCH; ++cc) m = fmaxf(m, pml[base + cc].x);
    float lsum = 0.0f, o = 0.0f;
    #pragma unroll
    for (int cc = 0; cc < NCH; ++cc) {
        float2 ml = pml[base + cc];
        float sc = __expf(ml.x - m);
        lsum += ml.y * sc;
        o    += po[(size_t)(base + cc) * DD + lane] * sc;
    }
    out[(((size_t)b * NT + u) * HH + h) * DD + lane] = o / lsum;
}

extern "C" void kernel_launch(void* const* d_in, const int* in_sizes, int n_in,
                              void* d_out, int out_size, void* d_ws, size_t ws_size,
                              hipStream_t stream) {
    const float* Q   = (const float*)d_in[0];
    const float* K   = (const float*)d_in[1];
    const float* V   = (const float*)d_in[2];
    const int*   idx = (const int*)d_in[3];
    float* out = (float*)d_out;

    char* ws = (char*)d_ws;
    float*  M    = (float*)ws;                        ws += (size_t)BB * HH * LL * sizeof(float);
    int*    topi = (int*)ws;                          ws += (size_t)BB * HH * NT * sizeof(int);
    float2* pml  = (float2*)ws;                       ws += (size_t)BB * HH * NT * NCH * sizeof(float2);
    float*  po   = (float*)ws;                        // 2.62 MB

    hipLaunchKernelGGL(compute_m_kernel, dim3(BB * LL), dim3(256), 0, stream,
                       Q, K, idx, M);
    hipLaunchKernelGGL(topk_kernel, dim3(BB * HH), dim3(256), 0, stream, M, topi);
    hipLaunchKernelGGL(attn_kernel, dim3(2 * BB * HH * NCH), dim3(256), 0, stream,
                       Q, K, V, topi, pml, po);
    hipLaunchKernelGGL(merge_kernel, dim3(BB * HH * NT / 4), dim3(256), 0, stream,
                       pml, po, out);
}

// Round 13
// 168.445 us; speedup vs baseline: 1.1749x; 1.0337x over previous
//
#include <hip/hip_runtime.h>
#include <hip/hip_bf16.h>

// Problem constants: B=4, L=2048, H=8, D=64, SAMPLE_K=N_TOP=40
#define BB 4
#define LL 2048
#define HH 8
#define DD 64
#define SK 40
#define NT 40
#define CH 256              // keys per attn chunk
#define NCH (LL / CH)       // 8 chunks per (b,h)
#define QH 20               // queries per attn block (40 split in 2)

#define WS 10               // samples per wave (4 waves x 10 = 40)
#define HB 68               // padded h-block stride in dwords (64 data + 4 pad)
#define RS (HH * HB)        // 544 dwords per row; 544%32==0
// Bank math (round 12 ERRATUM): reading s_lo*516+h*64+q*16 put all starts in
// banks {0,16} -> 16-way conflicts (7.86M measured). With h*68: starts at
// (4h+16q)%32 = 8 banks x 4/32 lanes — the round-8 shape that measured 0.

// ---------------------------------------------------------------------------
// Kernel 1: M[bh][l] = max_s(q . k_{idx[l,s]}) - (sum_s q . k_{idx[l,s]}) / L
// Block = (b,l), XCD-swizzled (each XCD pair serves one b -> K[b] L2-resident).
// WAVE-PRIVATE pipeline, VGPR staging (round 11: DMA w/o vmcnt wait raced the
// ds_read; VGPR->ds_write keeps deps compiler-visible; the LDS write->read
// hazard is per-wave: explicit s_waitcnt lgkmcnt(0)). No block barriers in
// the pipeline. Wave owns 10 samples in 5 double-buffered pairs.
// ---------------------------------------------------------------------------
__global__ __launch_bounds__(256) void compute_m_kernel(
        const float* __restrict__ Q, const float* __restrict__ K,
        const int* __restrict__ idx, float* __restrict__ M) {
    __shared__ float kbuf[4][2][2 * RS];   // 4 waves x 2 slots x 2 rows = 34 KB
    __shared__ int sidx[SK];
    __shared__ float2 mlpart[4][HH];

    int blk = blockIdx.x;
    int x = blk & 7, g = blk >> 3;
    int b = x >> 1;                    // XCD pair -> batch
    int l = (g << 1) | (x & 1);
    int t = threadIdx.x;

    if (t < SK) sidx[t] = idx[(size_t)l * SK + t];

    int lane = t & 63, w = t >> 6;
    int s_lo = lane >> 5;              // which sample of the pair
    int h    = (lane >> 2) & 7;        // head
    int q    = lane & 3;               // 16-dim quarter

    const float4* Qb = (const float4*)(Q + ((size_t)b * LL + l) * 512 + h * 64 + q * 16);
    float4 qf0 = Qb[0], qf1 = Qb[1], qf2 = Qb[2], qf3 = Qb[3];

    const float* Kb = K + (size_t)b * LL * 512;

    int r  = lane >> 5;                // staging row of the pair
    int cw = lane & 31;
    int a  = cw >> 4;                  // 0/1: which 64-dword half-pair the lane starts in
    int c4 = (4 * cw) & 63;           // within-block dword offset
    __syncthreads();                   // sidx ready

    float4 g0, g1, g2, g3;
    #define LOADP(p) do {                                                       \
        const float* src = Kb + (size_t)sidx[w * WS + (p) * 2 + r] * 512        \
                         + cw * 4;                                              \
        g0 = *(const float4*)(src);                                             \
        g1 = *(const float4*)(src + 128);                                       \
        g2 = *(const float4*)(src + 256);                                       \
        g3 = *(const float4*)(src + 384);                                       \
    } while (0)
    // global dword gd = 4cw + 128i lands in h-block h' = a + 2i at offset c4
    #define WRITEP(slot) do {                                                   \
        float* base = &kbuf[w][slot][r * RS + c4];                              \
        *(float4*)(base + (a + 0) * HB) = g0;                                   \
        *(float4*)(base + (a + 2) * HB) = g1;                                   \
        *(float4*)(base + (a + 4) * HB) = g2;                                   \
        *(float4*)(base + (a + 6) * HB) = g3;                                   \
    } while (0)

    LOADP(0);
    WRITEP(0);

    float mx = -INFINITY, sm = 0.0f;
    #pragma unroll
    for (int p = 0; p < WS / 2; ++p) {
        if (p < WS / 2 - 1) LOADP(p + 1);          // global loads in flight
        asm volatile("s_waitcnt lgkmcnt(0)" ::: "memory");  // slot p&1 landed (per-wave)
        const float* kb = &kbuf[w][p & 1][s_lo * RS + h * HB + q * 16];
        float4 k0 = *(const float4*)(kb);
        float4 k1 = *(const float4*)(kb + 4);
        float4 k2 = *(const float4*)(kb + 8);
        float4 k3 = *(const float4*)(kb + 12);
        float pd = qf0.x * k0.x + qf0.y * k0.y + qf0.z * k0.z + qf0.w * k0.w
                 + qf1.x * k1.x + qf1.y * k1.y + qf1.z * k1.z + qf1.w * k1.w
                 + qf2.x * k2.x + qf2.y * k2.y + qf2.z * k2.z + qf2.w * k2.w
                 + qf3.x * k3.x + qf3.y * k3.y + qf3.z * k3.z + qf3.w * k3.w;
        pd += __shfl_xor(pd, 1, 64);   // quad combine -> full dot
        pd += __shfl_xor(pd, 2, 64);
        mx = fmaxf(mx, pd);
        sm += pd;
        if (p < WS / 2 - 1) WRITEP((p + 1) & 1);   // compiler waits vmcnt for g*
    }
    #undef LOADP
    #undef WRITEP

    // merge the two pair-halves (lane ^ 32 holds the other sample's stats)
    mx = fmaxf(mx, __shfl_xor(mx, 32, 64));
    sm += __shfl_xor(sm, 32, 64);

    if ((lane & 0x23) == 0)            // q==0 && s_lo==0 -> lane = h*4
        mlpart[w][h] = make_float2(mx, sm);
    __syncthreads();

    if (t < HH) {
        float MX = -INFINITY, SM = 0.0f;
        #pragma unroll
        for (int w2 = 0; w2 < 4; ++w2) {
            float2 ml = mlpart[w2][t];
            MX = fmaxf(MX, ml.x);
            SM += ml.y;
        }
        M[((size_t)b * HH + t) * LL + l] = MX - SM * (1.0f / (float)LL);
    }
}

// ---------------------------------------------------------------------------
// Kernel 2: top-40 per (b,h), lower index wins ties. Incremental argmax.
// ---------------------------------------------------------------------------
__global__ __launch_bounds__(256) void topk_kernel(const float* __restrict__ M,
                                                   int* __restrict__ topi) {
    __shared__ unsigned long long keys[LL];   // 16 KB
    __shared__ unsigned long long wmax[4];
    __shared__ int win;
    int bh = blockIdx.x;
    int t  = threadIdx.x;
    int lane = t & 63, w = t >> 6;

    unsigned long long kmax = 0ULL;
    #pragma unroll
    for (int j = 0; j < 8; ++j) {
        int i = t + 256 * j;
        unsigned int bits = __float_as_uint(M[(size_t)bh * LL + i]);
        bits = (bits & 0x80000000u) ? ~bits : (bits | 0x80000000u);
        unsigned long long k = ((unsigned long long)bits << 11)
                             | (unsigned int)(LL - 1 - i);
        keys[i] = k;
        if (k > kmax) kmax = k;
    }
    __syncthreads();

    for (int u = 0; u < NT; ++u) {
        unsigned long long k = kmax;
        #pragma unroll
        for (int off = 32; off >= 1; off >>= 1) {
            unsigned long long o = __shfl_xor(k, off, 64);
            if (o > k) k = o;
        }
        if (lane == 0) wmax[w] = k;
        __syncthreads();
        if (t == 0) {
            unsigned long long k0 = wmax[0];
            if (wmax[1] > k0) k0 = wmax[1];
            if (wmax[2] > k0) k0 = wmax[2];
            if (wmax[3] > k0) k0 = wmax[3];
            int i = (LL - 1) - (int)(k0 & 0x7FF);
            topi[bh * NT + u] = i;
            keys[i] = 0ULL;
            win = i;
        }
        __syncthreads();
        if ((win & 255) == t) {          // only the owner rescans
            kmax = 0ULL;
            #pragma unroll
            for (int j = 0; j < 8; ++j) {
                unsigned long long kk = keys[t + 256 * j];
                if (kk > kmax) kmax = kk;
            }
        }
    }
}

// ---------------------------------------------------------------------------
// Kernel 3: flash-chunked attention, query-split.
// __launch_bounds__(256,3) keeps kreg/vcol in registers (round 7 spill fix).
// (m,l) packed float2 store (round 8 granule-waste fix).
// ---------------------------------------------------------------------------
__global__ __launch_bounds__(256, 3) void attn_kernel(
        const float* __restrict__ Q, const float* __restrict__ K,
        const float* __restrict__ V, const int* __restrict__ topi,
        float2* __restrict__ pml, float* __restrict__ po) {
    __shared__ float  qs[QH][DD];        //  5120 B
    __shared__ float4 e4buf[4][64];      //  4096 B
    __shared__ float  oarea[4][QH][DD];  // 20480 B
    __shared__ float  mlarea[4][QH][2];  //   640 B

    int blk = blockIdx.x;
    int qh  = blk >> 8;                  // 0/1 query half
    int cc2 = blk & 255;
    int c   = cc2 & (NCH - 1);
    int bh  = cc2 >> 3;
    int h = bh & (HH - 1), b = bh >> 3;
    int t = threadIdx.x, lane = t & 63, w = t >> 6;
    int u0 = qh * QH;

    for (int i = t; i < QH * DD; i += 256) {
        int u = i >> 6, d = i & 63;
        int lq = topi[bh * NT + u0 + u];
        qs[u][d] = Q[(((size_t)b * LL + lq) * HH + h) * DD + d];
    }

    int key = c * CH + w * 64 + lane;
    const float4* kr = (const float4*)&K[(((size_t)b * LL + key) * HH + h) * DD];
    float4 kreg[16];
    #pragma unroll
    for (int j = 0; j < 16; ++j) kreg[j] = kr[j];

    float vcol[64];
    const float* vb = &V[(((size_t)b * LL + c * CH + w * 64) * HH + h) * DD + lane];
    #pragma unroll
    for (int j = 0; j < 64; ++j) vcol[j] = vb[(size_t)j * HH * DD];

    __syncthreads();   // qs ready

    for (int uq = 0; uq < QH / 4; ++uq) {
        float o0 = 0, o1 = 0, o2 = 0, o3 = 0;
        float mv0, mv1, mv2, mv3, lv0, lv1, lv2, lv3;
        float4 ev;
        #pragma unroll
        for (int j = 0; j < 4; ++j) {
            int u = uq * 4 + j;
            const float4* q4 = (const float4*)&qs[u][0];
            float s = 0.0f;
            #pragma unroll
            for (int cc = 0; cc < 16; ++cc) {
                float4 qv = q4[cc];
                s += qv.x * kreg[cc].x + qv.y * kreg[cc].y
                   + qv.z * kreg[cc].z + qv.w * kreg[cc].w;
            }
            s *= 0.125f;   // 1/sqrt(64)
            float m = s;
            #pragma unroll
            for (int off = 32; off >= 1; off >>= 1)
                m = fmaxf(m, __shfl_xor(m, off, 64));
            float e = __expf(s - m);
            float ls = e;
            #pragma unroll
            for (int off = 32; off >= 1; off >>= 1)
                ls += __shfl_xor(ls, off, 64);
            if (j == 0) { mv0 = m; lv0 = ls; ev.x = e; }
            if (j == 1) { mv1 = m; lv1 = ls; ev.y = e; }
            if (j == 2) { mv2 = m; lv2 = ls; ev.z = e; }
            if (j == 3) { mv3 = m; lv3 = ls; ev.w = e; }
        }
        e4buf[w][lane] = ev;
        asm volatile("s_waitcnt lgkmcnt(0)" ::: "memory");
        #pragma unroll
        for (int l2 = 0; l2 < 64; ++l2) {      // FULL unroll: vcol static
            float4 e = e4buf[w][l2];
            float  v = vcol[l2];
            o0 += e.x * v; o1 += e.y * v; o2 += e.z * v; o3 += e.w * v;
        }
        oarea[w][uq * 4 + 0][lane] = o0;
        oarea[w][uq * 4 + 1][lane] = o1;
        oarea[w][uq * 4 + 2][lane] = o2;
        oarea[w][uq * 4 + 3][lane] = o3;
        if (lane == 0) {
            mlarea[w][uq * 4 + 0][0] = mv0; mlarea[w][uq * 4 + 0][1] = lv0;
            mlarea[w][uq * 4 + 1][0] = mv1; mlarea[w][uq * 4 + 1][1] = lv1;
            mlarea[w][uq * 4 + 2][0] = mv2; mlarea[w][uq * 4 + 2][1] = lv2;
            mlarea[w][uq * 4 + 3][0] = mv3; mlarea[w][uq * 4 + 3][1] = lv3;
        }
    }
    __syncthreads();

    for (int i = t; i < QH * DD; i += 256) {
        int u = i >> 6, d = i & 63;
        float m0 = mlarea[0][u][0], m1 = mlarea[1][u][0];
        float m2 = mlarea[2][u][0], m3 = mlarea[3][u][0];
        float mb = fmaxf(fmaxf(m0, m1), fmaxf(m2, m3));
        float s0 = __expf(m0 - mb), s1 = __expf(m1 - mb);
        float s2 = __expf(m2 - mb), s3 = __expf(m3 - mb);
        float ob = oarea[0][u][d] * s0 + oarea[1][u][d] * s1
                 + oarea[2][u][d] * s2 + oarea[3][u][d] * s3;
        int gu = u0 + u;
        po[((size_t)(bh * NT + gu) * NCH + c) * DD + d] = ob;
        if (d == 0) {
            float lb = mlarea[0][u][1] * s0 + mlarea[1][u][1] * s1
                     + mlarea[2][u][1] * s2 + mlarea[3][u][1] * s3;
            pml[(bh * NT + gu) * NCH + c] = make_float2(mb, lb);
        }
    }
}

// ---------------------------------------------------------------------------
// Kernel 4: merge chunk partials. One wave per (bh,u), lane = d.
// ---------------------------------------------------------------------------
__global__ __launch_bounds__(256) void merge_kernel(
        const float2* __restrict__ pml, const float* __restrict__ po,
        float* __restrict__ out) {
    int wid  = blockIdx.x * 4 + (threadIdx.x >> 6);
    int lane = threadIdx.x & 63;
    int u  = wid % NT;
    int bh = wid / NT;
    int h = bh & (HH - 1), b = bh >> 3;
    int base = (bh * NT + u) * NCH;

    float m = -INFINITY;
    #pragma unroll
    for (int cc = 0; cc < NCH; ++cc) m = fmaxf(m, pml[base + cc].x);
    float lsum = 0.0f, o = 0.0f;
    #pragma unroll
    for (int cc = 0; cc < NCH; ++cc) {
        float2 ml = pml[base + cc];
        float sc = __expf(ml.x - m);
        lsum += ml.y * sc;
        o    += po[(size_t)(base + cc) * DD + lane] * sc;
    }
    out[(((size_t)b * NT + u) * HH + h) * DD + lane] = o / lsum;
}

extern "C" void kernel_launch(void* const* d_in, const int* in_sizes, int n_in,
                              void* d_out, int out_size, void* d_ws, size_t ws_size,
                              hipStream_t stream) {
    const float* Q   = (const float*)d_in[0];
    const float* K   = (const float*)d_in[1];
    const float* V   = (const float*)d_in[2];
    const int*   idx = (const int*)d_in[3];
    float* out = (float*)d_out;

    char* ws = (char*)d_ws;
    float*  M    = (float*)ws;                        ws += (size_t)BB * HH * LL * sizeof(float);
    int*    topi = (int*)ws;                          ws += (size_t)BB * HH * NT * sizeof(int);
    float2* pml  = (float2*)ws;                       ws += (size_t)BB * HH * NT * NCH * sizeof(float2);
    float*  po   = (float*)ws;                        // 2.62 MB

    hipLaunchKernelGGL(compute_m_kernel, dim3(BB * LL), dim3(256), 0, stream,
                       Q, K, idx, M);
    hipLaunchKernelGGL(topk_kernel, dim3(BB * HH), dim3(256), 0, stream, M, topi);
    hipLaunchKernelGGL(attn_kernel, dim3(2 * BB * HH * NCH), dim3(256), 0, stream,
                       Q, K, V, topi, pml, po);
    hipLaunchKernelGGL(merge_kernel, dim3(BB * HH * NT / 4), dim3(256), 0, stream,
                       pml, po, out);
}

// Round 14
// 167.889 us; speedup vs baseline: 1.1788x; 1.0033x over previous
//
#include <hip/hip_runtime.h>
#include <hip/hip_bf16.h>

// Problem constants: B=4, L=2048, H=8, D=64, SAMPLE_K=N_TOP=40
#define BB 4
#define LL 2048
#define HH 8
#define DD 64
#define SK 40
#define NT 40
#define CH 256              // keys per attn chunk
#define NCH (LL / CH)       // 8 chunks per (b,h)
#define QH 20               // queries per attn block (40 split in 2)

#define WS 10               // samples per wave (4 waves x 10 = 40)
#define HB 68               // padded h-block stride in dwords (64 data + 4 pad)
#define RS (HH * HB)        // 544 dwords per row; bank-conflict-free (round 13: 7.86M -> 0)

// ---------------------------------------------------------------------------
// Kernel 1: M[bh][l] = max_s(q . k_{idx[l,s]}) - (sum_s q . k_{idx[l,s]}) / L
// Block = (b,l), XCD-swizzled. WAVE-PRIVATE pipeline, VGPR staging, now with
// TWO register sets (2 sample-pairs in flight): loads for pair p+2 are issued
// a full phase before their ds_write consumes them, hiding ~200-400 cyc L2
// latency (round 13 model: single-depth prefetch left ~200 cyc/phase exposed
// -> 43 us; deeper pipeline targets ~31). Hazards stay per-wave: explicit
// lgkmcnt(0) at each consume orders prior ds ops; ds_write's vmcnt dependence
// is register-carried (compiler-visible). No block barriers in the pipeline.
// Schedule (pairs 0..4, slots S0/S1, reg sets A/B):
//   LOADA(0) LOADB(1) WRITEA(S0)
//   p0: LOADA(2) consume(S0) WRITEB(S1)
//   p1: LOADB(3) consume(S1) WRITEA(S0)
//   p2: LOADA(4) consume(S0) WRITEB(S1)
//   p3:          consume(S1) WRITEA(S0)
//   p4:          consume(S0)
// ---------------------------------------------------------------------------
__global__ __launch_bounds__(256) void compute_m_kernel(
        const float* __restrict__ Q, const float* __restrict__ K,
        const int* __restrict__ idx, float* __restrict__ M) {
    __shared__ float kbuf[4][2][2 * RS];   // 4 waves x 2 slots x 2 rows = 34.8 KB
    __shared__ int sidx[SK];
    __shared__ float2 mlpart[4][HH];

    int blk = blockIdx.x;
    int x = blk & 7, g = blk >> 3;
    int b = x >> 1;                    // XCD pair -> batch
    int l = (g << 1) | (x & 1);
    int t = threadIdx.x;

    if (t < SK) sidx[t] = idx[(size_t)l * SK + t];

    int lane = t & 63, w = t >> 6;
    int s_lo = lane >> 5;              // which sample of the pair
    int h    = (lane >> 2) & 7;        // head
    int q    = lane & 3;               // 16-dim quarter

    const float4* Qb = (const float4*)(Q + ((size_t)b * LL + l) * 512 + h * 64 + q * 16);
    float4 qf0 = Qb[0], qf1 = Qb[1], qf2 = Qb[2], qf3 = Qb[3];

    const float* Kb = K + (size_t)b * LL * 512;

    int r  = lane >> 5;                // staging row of the pair
    int cw = lane & 31;
    int av = cw >> 4;                  // 0/1: which 64-dword half the lane starts in
    int c4 = (4 * cw) & 63;            // within-block dword offset
    __syncthreads();                   // sidx ready

    float4 ra0, ra1, ra2, ra3;         // reg set A (pairs 0,2,4)
    float4 rb0, rb1, rb2, rb3;         // reg set B (pairs 1,3)

    #define LOADX(p, d0, d1, d2, d3) do {                                       \
        const float* src = Kb + (size_t)sidx[w * WS + (p) * 2 + r] * 512        \
                         + cw * 4;                                              \
        d0 = *(const float4*)(src);                                             \
        d1 = *(const float4*)(src + 128);                                       \
        d2 = *(const float4*)(src + 256);                                       \
        d3 = *(const float4*)(src + 384);                                       \
    } while (0)
    #define WRITEX(slot, d0, d1, d2, d3) do {                                   \
        float* base = &kbuf[w][slot][r * RS + c4];                              \
        *(float4*)(base + (av + 0) * HB) = d0;                                  \
        *(float4*)(base + (av + 2) * HB) = d1;                                  \
        *(float4*)(base + (av + 4) * HB) = d2;                                  \
        *(float4*)(base + (av + 6) * HB) = d3;                                  \
    } while (0)
    #define CONSUME(slot) do {                                                  \
        asm volatile("s_waitcnt lgkmcnt(0)" ::: "memory");                      \
        const float* kb = &kbuf[w][slot][s_lo * RS + h * HB + q * 16];          \
        float4 k0 = *(const float4*)(kb);                                       \
        float4 k1 = *(const float4*)(kb + 4);                                   \
        float4 k2 = *(const float4*)(kb + 8);                                   \
        float4 k3 = *(const float4*)(kb + 12);                                  \
        float pd = qf0.x*k0.x + qf0.y*k0.y + qf0.z*k0.z + qf0.w*k0.w            \
                 + qf1.x*k1.x + qf1.y*k1.y + qf1.z*k1.z + qf1.w*k1.w            \
                 + qf2.x*k2.x + qf2.y*k2.y + qf2.z*k2.z + qf2.w*k2.w            \
                 + qf3.x*k3.x + qf3.y*k3.y + qf3.z*k3.z + qf3.w*k3.w;           \
        pd += __shfl_xor(pd, 1, 64);                                            \
        pd += __shfl_xor(pd, 2, 64);                                            \
        mx = fmaxf(mx, pd);                                                     \
        sm += pd;                                                               \
    } while (0)

    float mx = -INFINITY, sm = 0.0f;

    LOADX(0, ra0, ra1, ra2, ra3);
    LOADX(1, rb0, rb1, rb2, rb3);
    WRITEX(0, ra0, ra1, ra2, ra3);     // stalls vmcnt for pair 0 only (once)

    LOADX(2, ra0, ra1, ra2, ra3);
    CONSUME(0);
    WRITEX(1, rb0, rb1, rb2, rb3);     // pair-1 loads are ~1 phase old

    LOADX(3, rb0, rb1, rb2, rb3);
    CONSUME(1);
    WRITEX(0, ra0, ra1, ra2, ra3);     // pair-2 loads ~1 phase old

    LOADX(4, ra0, ra1, ra2, ra3);
    CONSUME(0);
    WRITEX(1, rb0, rb1, rb2, rb3);

    CONSUME(1);
    WRITEX(0, ra0, ra1, ra2, ra3);

    CONSUME(0);

    #undef LOADX
    #undef WRITEX
    #undef CONSUME

    // merge the two pair-halves (lane ^ 32 holds the other sample's stats)
    mx = fmaxf(mx, __shfl_xor(mx, 32, 64));
    sm += __shfl_xor(sm, 32, 64);

    if ((lane & 0x23) == 0)            // q==0 && s_lo==0 -> lane = h*4
        mlpart[w][h] = make_float2(mx, sm);
    __syncthreads();

    if (t < HH) {
        float MX = -INFINITY, SM = 0.0f;
        #pragma unroll
        for (int w2 = 0; w2 < 4; ++w2) {
            float2 ml = mlpart[w2][t];
            MX = fmaxf(MX, ml.x);
            SM += ml.y;
        }
        M[((size_t)b * HH + t) * LL + l] = MX - SM * (1.0f / (float)LL);
    }
}

// ---------------------------------------------------------------------------
// Kernel 2: top-40 per (b,h), lower index wins ties. Incremental argmax.
// ---------------------------------------------------------------------------
__global__ __launch_bounds__(256) void topk_kernel(const float* __restrict__ M,
                                                   int* __restrict__ topi) {
    __shared__ unsigned long long keys[LL];   // 16 KB
    __shared__ unsigned long long wmax[4];
    __shared__ int win;
    int bh = blockIdx.x;
    int t  = threadIdx.x;
    int lane = t & 63, w = t >> 6;

    unsigned long long kmax = 0ULL;
    #pragma unroll
    for (int j = 0; j < 8; ++j) {
        int i = t + 256 * j;
        unsigned int bits = __float_as_uint(M[(size_t)bh * LL + i]);
        bits = (bits & 0x80000000u) ? ~bits : (bits | 0x80000000u);
        unsigned long long k = ((unsigned long long)bits << 11)
                             | (unsigned int)(LL - 1 - i);
        keys[i] = k;
        if (k > kmax) kmax = k;
    }
    __syncthreads();

    for (int u = 0; u < NT; ++u) {
        unsigned long long k = kmax;
        #pragma unroll
        for (int off = 32; off >= 1; off >>= 1) {
            unsigned long long o = __shfl_xor(k, off, 64);
            if (o > k) k = o;
        }
        if (lane == 0) wmax[w] = k;
        __syncthreads();
        if (t == 0) {
            unsigned long long k0 = wmax[0];
            if (wmax[1] > k0) k0 = wmax[1];
            if (wmax[2] > k0) k0 = wmax[2];
            if (wmax[3] > k0) k0 = wmax[3];
            int i = (LL - 1) - (int)(k0 & 0x7FF);
            topi[bh * NT + u] = i;
            keys[i] = 0ULL;
            win = i;
        }
        __syncthreads();
        if ((win & 255) == t) {          // only the owner rescans
            kmax = 0ULL;
            #pragma unroll
            for (int j = 0; j < 8; ++j) {
                unsigned long long kk = keys[t + 256 * j];
                if (kk > kmax) kmax = kk;
            }
        }
    }
}

// ---------------------------------------------------------------------------
// Kernel 3: flash-chunked attention, query-split.
// __launch_bounds__(256,3) keeps kreg/vcol in registers (round 7 spill fix).
// (m,l) packed float2 store (round 8 granule-waste fix).
// ---------------------------------------------------------------------------
__global__ __launch_bounds__(256, 3) void attn_kernel(
        const float* __restrict__ Q, const float* __restrict__ K,
        const float* __restrict__ V, const int* __restrict__ topi,
        float2* __restrict__ pml, float* __restrict__ po) {
    __shared__ float  qs[QH][DD];        //  5120 B
    __shared__ float4 e4buf[4][64];      //  4096 B
    __shared__ float  oarea[4][QH][DD];  // 20480 B
    __shared__ float  mlarea[4][QH][2];  //   640 B

    int blk = blockIdx.x;
    int qh  = blk >> 8;                  // 0/1 query half
    int cc2 = blk & 255;
    int c   = cc2 & (NCH - 1);
    int bh  = cc2 >> 3;
    int h = bh & (HH - 1), b = bh >> 3;
    int t = threadIdx.x, lane = t & 63, w = t >> 6;
    int u0 = qh * QH;

    for (int i = t; i < QH * DD; i += 256) {
        int u = i >> 6, d = i & 63;
        int lq = topi[bh * NT + u0 + u];
        qs[u][d] = Q[(((size_t)b * LL + lq) * HH + h) * DD + d];
    }

    int key = c * CH + w * 64 + lane;
    const float4* kr = (const float4*)&K[(((size_t)b * LL + key) * HH + h) * DD];
    float4 kreg[16];
    #pragma unroll
    for (int j = 0; j < 16; ++j) kreg[j] = kr[j];

    float vcol[64];
    const float* vb = &V[(((size_t)b * LL + c * CH + w * 64) * HH + h) * DD + lane];
    #pragma unroll
    for (int j = 0; j < 64; ++j) vcol[j] = vb[(size_t)j * HH * DD];

    __syncthreads();   // qs ready

    for (int uq = 0; uq < QH / 4; ++uq) {
        float o0 = 0, o1 = 0, o2 = 0, o3 = 0;
        float mv0, mv1, mv2, mv3, lv0, lv1, lv2, lv3;
        float4 ev;
        #pragma unroll
        for (int j = 0; j < 4; ++j) {
            int u = uq * 4 + j;
            const float4* q4 = (const float4*)&qs[u][0];
            float s = 0.0f;
            #pragma unroll
            for (int cc = 0; cc < 16; ++cc) {
                float4 qv = q4[cc];
                s += qv.x * kreg[cc].x + qv.y * kreg[cc].y
                   + qv.z * kreg[cc].z + qv.w * kreg[cc].w;
            }
            s *= 0.125f;   // 1/sqrt(64)
            float m = s;
            #pragma unroll
            for (int off = 32; off >= 1; off >>= 1)
                m = fmaxf(m, __shfl_xor(m, off, 64));
            float e = __expf(s - m);
            float ls = e;
            #pragma unroll
            for (int off = 32; off >= 1; off >>= 1)
                ls += __shfl_xor(ls, off, 64);
            if (j == 0) { mv0 = m; lv0 = ls; ev.x = e; }
            if (j == 1) { mv1 = m; lv1 = ls; ev.y = e; }
            if (j == 2) { mv2 = m; lv2 = ls; ev.z = e; }
            if (j == 3) { mv3 = m; lv3 = ls; ev.w = e; }
        }
        e4buf[w][lane] = ev;
        asm volatile("s_waitcnt lgkmcnt(0)" ::: "memory");
        #pragma unroll
        for (int l2 = 0; l2 < 64; ++l2) {      // FULL unroll: vcol static
            float4 e = e4buf[w][l2];
            float  v = vcol[l2];
            o0 += e.x * v; o1 += e.y * v; o2 += e.z * v; o3 += e.w * v;
        }
        oarea[w][uq * 4 + 0][lane] = o0;
        oarea[w][uq * 4 + 1][lane] = o1;
        oarea[w][uq * 4 + 2][lane] = o2;
        oarea[w][uq * 4 + 3][lane] = o3;
        if (lane == 0) {
            mlarea[w][uq * 4 + 0][0] = mv0; mlarea[w][uq * 4 + 0][1] = lv0;
            mlarea[w][uq * 4 + 1][0] = mv1; mlarea[w][uq * 4 + 1][1] = lv1;
            mlarea[w][uq * 4 + 2][0] = mv2; mlarea[w][uq * 4 + 2][1] = lv2;
            mlarea[w][uq * 4 + 3][0] = mv3; mlarea[w][uq * 4 + 3][1] = lv3;
        }
    }
    __syncthreads();

    for (int i = t; i < QH * DD; i += 256) {
        int u = i >> 6, d = i & 63;
        float m0 = mlarea[0][u][0], m1 = mlarea[1][u][0];
        float m2 = mlarea[2][u][0], m3 = mlarea[3][u][0];
        float mb = fmaxf(fmaxf(m0, m1), fmaxf(m2, m3));
        float s0 = __expf(m0 - mb), s1 = __expf(m1 - mb);
        float s2 = __expf(m2 - mb), s3 = __expf(m3 - mb);
        float ob = oarea[0][u][d] * s0 + oarea[1][u][d] * s1
                 + oarea[2][u][d] * s2 + oarea[3][u][d] * s3;
        int gu = u0 + u;
        po[((size_t)(bh * NT + gu) * NCH + c) * DD + d] = ob;
        if (d == 0) {
            float lb = mlarea[0][u][1] * s0 + mlarea[1][u][1] * s1
                     + mlarea[2][u][1] * s2 + mlarea[3][u][1] * s3;
            pml[(bh * NT + gu) * NCH + c] = make_float2(mb, lb);
        }
    }
}

// ---------------------------------------------------------------------------
// Kernel 4: merge chunk partials. One wave per (bh,u), lane = d.
// ---------------------------------------------------------------------------
__global__ __launch_bounds__(256) void merge_kernel(
        const float2* __restrict__ pml, const float* __restrict__ po,
        float* __restrict__ out) {
    int wid  = blockIdx.x * 4 + (threadIdx.x >> 6);
    int lane = threadIdx.x & 63;
    int u  = wid % NT;
    int bh = wid / NT;
    int h = bh & (HH - 1), b = bh >> 3;
    int base = (bh * NT + u) * NCH;

    float m = -INFINITY;
    #pragma unroll
    for (int cc = 0; cc < NCH; ++cc) m = fmaxf(m, pml[base + cc].x);
    float lsum = 0.0f, o = 0.0f;
    #pragma unroll
    for (int cc = 0; cc < NCH; ++cc) {
        float2 ml = pml[base + cc];
        float sc = __expf(ml.x - m);
        lsum += ml.y * sc;
        o    += po[(size_t)(base + cc) * DD + lane] * sc;
    }
    out[(((size_t)b * NT + u) * HH + h) * DD + lane] = o / lsum;
}

extern "C" void kernel_launch(void* const* d_in, const int* in_sizes, int n_in,
                              void* d_out, int out_size, void* d_ws, size_t ws_size,
                              hipStream_t stream) {
    const float* Q   = (const float*)d_in[0];
    const float* K   = (const float*)d_in[1];
    const float* V   = (const float*)d_in[2];
    const int*   idx = (const int*)d_in[3];
    float* out = (float*)d_out;

    char* ws = (char*)d_ws;
    float*  M    = (float*)ws;                        ws += (size_t)BB * HH * LL * sizeof(float);
    int*    topi = (int*)ws;                          ws += (size_t)BB * HH * NT * sizeof(int);
    float2* pml  = (float2*)ws;                       ws += (size_t)BB * HH * NT * NCH * sizeof(float2);
    float*  po   = (float*)ws;                        // 2.62 MB

    hipLaunchKernelGGL(compute_m_kernel, dim3(BB * LL), dim3(256), 0, stream,
                       Q, K, idx, M);
    hipLaunchKernelGGL(topk_kernel, dim3(BB * HH), dim3(256), 0, stream, M, topi);
    hipLaunchKernelGGL(attn_kernel, dim3(2 * BB * HH * NCH), dim3(256), 0, stream,
                       Q, K, V, topi, pml, po);
    hipLaunchKernelGGL(merge_kernel, dim3(BB * HH * NT / 4), dim3(256), 0, stream,
                       pml, po, out);
}